// Round 6
// baseline (218.961 us; speedup 1.0000x reference)
//
#include <hip/hip_runtime.h>

typedef unsigned short u16;
typedef __attribute__((ext_vector_type(8))) short bf16x8;
typedef __attribute__((ext_vector_type(4))) float f32x4;

#define B_   8
#define S_   2048
#define IN_  256
#define D_   1024
#define OUT_ 256
#define KC_  32          // flash k-chunks
#define RC_  64          // rows per chunk

// ---- workspace offsets (bytes), total ~3.3 MB ----
#define OFF_WITB  0UL          // WiT tiles: 8 tr x 4 ks x 8192 u16 = 512K
#define OFF_WOTB  524288UL     // WoT tiles: 2 tr x 16 ks x 8192 u16 = 512K
#define OFF_HLAST 1048576UL    // 8x1024 f32 = 32K  (exact f32 h_last)
#define OFF_QV    1081344UL    // 8x1024 f32 = 32K  (Q = h_last@Wq + bq)
#define OFF_UV    1114112UL    // 8x1024 f32 = 32K  (u = Wk@Q)
#define OFF_AWO   1146880UL    // 1024x256 f32 = 1M (Wv @ Wo)
#define OFF_CVOP  2195456UL    // 16x256 f32
#define OFF_CVO   2211840UL    // 256 f32
#define OFF_PART  2215936UL    // 256x1024 f32 = 1M
#define OFF_MSUM  3264512UL    // 256x2 f32

static __device__ __forceinline__ float bf2f(u16 u) {
    union { unsigned i; float f; } x; x.i = ((unsigned)u) << 16; return x.f;
}
static __device__ __forceinline__ u16 f2bf(float f) {
    union { float f; unsigned i; } x; x.f = f;
    unsigned r = x.i + 0x7FFFu + ((x.i >> 16) & 1u);
    return (u16)(r >> 16);
}
static __device__ __forceinline__ float2 bf2x2(unsigned p) {
    union { unsigned i; float f; } a, b;
    a.i = p << 16;
    b.i = p & 0xFFFF0000u;
    float2 r; r.x = a.f; r.y = b.f; return r;
}

// Tiled-swizzled bf16 operand layout: element (rr in [0,128), cc in [0,64)) of tile
// (tr, ks) lives at u16 index (tr*KT + ks)*8192 + rr*64 + (((cc>>3) ^ (rr&7))<<3) + (cc&7).

// ================= K1: WiT/WoT prep, h_last (f32 exact), cvop =================
// blk 0..63   : WiT transpose -> WiTb
// blk 64..127 : WoT transpose -> WoTb
// blk 128..135: h_last[b] = x[b,S-1,:] @ Wi + bi   (f32)
// blk 136..151: cvop partials (bv @ Wo)
__global__ __launch_bounds__(256) void k1(const float* __restrict__ x,
                                          const float* __restrict__ Wi, u16* __restrict__ WiTb,
                                          const float* __restrict__ bi, float* __restrict__ hlast,
                                          const float* __restrict__ Wo, u16* __restrict__ WoTb,
                                          const float* __restrict__ bv, float* __restrict__ cvop) {
    __shared__ float t64[64][65];
    const int blk = blockIdx.x, tid = threadIdx.x;
    if (blk < 64) {
        // WiT[n][k] = Wi[k][n]; Wi is [256][1024].  KT=4.
        const int n0 = (blk & 15) * 64, k0 = (blk >> 4) * 64;
        const int cc = tid & 63, rr = tid >> 6;
#pragma unroll
        for (int p = 0; p < 16; ++p) { int r = p * 4 + rr; t64[r][cc] = Wi[(k0 + r) * 1024 + n0 + cc]; }
        __syncthreads();
        const int ks = k0 >> 6;
#pragma unroll
        for (int g = 0; g < 2; ++g) {
            int it = g * 256 + tid;
            int nn = it >> 3, grp = it & 7;
            int n = n0 + nn, tr = n >> 7, rrow = n & 127;
            int4 pk;
            pk.x = (int)f2bf(t64[grp * 8 + 0][nn]) | ((int)f2bf(t64[grp * 8 + 1][nn]) << 16);
            pk.y = (int)f2bf(t64[grp * 8 + 2][nn]) | ((int)f2bf(t64[grp * 8 + 3][nn]) << 16);
            pk.z = (int)f2bf(t64[grp * 8 + 4][nn]) | ((int)f2bf(t64[grp * 8 + 5][nn]) << 16);
            pk.w = (int)f2bf(t64[grp * 8 + 6][nn]) | ((int)f2bf(t64[grp * 8 + 7][nn]) << 16);
            *reinterpret_cast<int4*>(&WiTb[(size_t)(tr * 4 + ks) * 8192 + rrow * 64 + ((grp ^ (rrow & 7)) << 3)]) = pk;
        }
    } else if (blk < 128) {
        // WoT[o][e] = Wo[e][o]; Wo is [1024][256].  KT=16.
        const int t = blk - 64;
        const int o0 = (t & 3) * 64, e0 = (t >> 2) * 64;
        const int cc = tid & 63, rr = tid >> 6;
#pragma unroll
        for (int p = 0; p < 16; ++p) { int r = p * 4 + rr; t64[r][cc] = Wo[(e0 + r) * 256 + o0 + cc]; }
        __syncthreads();
        const int ks = e0 >> 6;
#pragma unroll
        for (int g = 0; g < 2; ++g) {
            int it = g * 256 + tid;
            int nn = it >> 3, grp = it & 7;
            int o = o0 + nn, tr = o >> 7, rrow = o & 127;
            int4 pk;
            pk.x = (int)f2bf(t64[grp * 8 + 0][nn]) | ((int)f2bf(t64[grp * 8 + 1][nn]) << 16);
            pk.y = (int)f2bf(t64[grp * 8 + 2][nn]) | ((int)f2bf(t64[grp * 8 + 3][nn]) << 16);
            pk.z = (int)f2bf(t64[grp * 8 + 4][nn]) | ((int)f2bf(t64[grp * 8 + 5][nn]) << 16);
            pk.w = (int)f2bf(t64[grp * 8 + 6][nn]) | ((int)f2bf(t64[grp * 8 + 7][nn]) << 16);
            *reinterpret_cast<int4*>(&WoTb[(size_t)(tr * 16 + ks) * 8192 + rrow * 64 + ((grp ^ (rrow & 7)) << 3)]) = pk;
        }
    } else if (blk < 136) {
        // h_last[b][c] = sum_dd x[b,S-1,dd]*Wi[dd][c] + bi[c]   (pure f32)
        const int b = blk - 128;
        __shared__ float xl[256];
        xl[tid] = x[((size_t)(b * S_ + S_ - 1)) * IN_ + tid];
        __syncthreads();
        float4 acc = *reinterpret_cast<const float4*>(&bi[tid * 4]);
#pragma unroll 4
        for (int dd = 0; dd < 256; ++dd) {
            float xv = xl[dd];
            float4 wv = *reinterpret_cast<const float4*>(&Wi[(size_t)dd * 1024 + tid * 4]);
            acc.x += xv * wv.x; acc.y += xv * wv.y; acc.z += xv * wv.z; acc.w += xv * wv.w;
        }
        *reinterpret_cast<float4*>(&hlast[b * 1024 + tid * 4]) = acc;
    } else {
        // cvop[chunk][o] = sum_{e in chunk} bv[e]*Wo[e][o]
        const int b2 = blk - 136;
        const int e0 = b2 * 64;
        float acc = 0.f;
        for (int e = 0; e < 64; ++e) acc += bv[e0 + e] * Wo[(size_t)(e0 + e) * 256 + tid];
        cvop[b2 * 256 + tid] = acc;
    }
}

// ---------------- staging helpers (256-thread / 4-wave version) ----------------
static __device__ __forceinline__ void stage_bf(const u16* gtile, u16* lbuf, int w, int l) {
    const u16* g = gtile + w * 512 + l * 8;
    u16* lp = lbuf + w * 512;
#pragma unroll
    for (int i = 0; i < 4; ++i)
        __builtin_amdgcn_global_load_lds((const __attribute__((address_space(1))) void*)(g + i * 2048),
                                         (__attribute__((address_space(3))) void*)(lp + i * 2048), 16, 0, 0);
}
static __device__ __forceinline__ void stage_f32(const float* src, int lds_, int ks, u16* lbuf, int tid) {
#pragma unroll
    for (int i = 0; i < 4; ++i) {
        int it = i * 256 + tid;
        int row = it >> 3, grp = it & 7;
        const float4* p = reinterpret_cast<const float4*>(&src[(size_t)row * lds_ + ks * 64 + grp * 8]);
        float4 v0 = p[0], v1 = p[1];
        int4 pk;
        pk.x = (int)f2bf(v0.x) | ((int)f2bf(v0.y) << 16);
        pk.y = (int)f2bf(v0.z) | ((int)f2bf(v0.w) << 16);
        pk.z = (int)f2bf(v1.x) | ((int)f2bf(v1.y) << 16);
        pk.w = (int)f2bf(v1.z) | ((int)f2bf(v1.w) << 16);
        *reinterpret_cast<int4*>(&lbuf[row * 64 + ((grp ^ (row & 7)) << 3)]) = pk;
    }
}

// ================= K2: Awo = Wv@Wo (MFMA) + Q = h_last@Wq + bq (matvec) =================
__global__ __launch_bounds__(256) void k2(const float* __restrict__ Wv, const u16* __restrict__ WoTb,
                                          float* __restrict__ Awo,
                                          const float* __restrict__ hlast, const float* __restrict__ Wq,
                                          const float* __restrict__ bq, float* __restrict__ Qv) {
    __shared__ u16 lds2[16384];
    const int blk = blockIdx.x, tid = threadIdx.x;
    if (blk < 16) {
        // Awo tile (mt 0..7, nt 0..1), KT=16, A = Wv f32 reg-staged, B = WoTb DMA
        u16* lA = lds2;
        u16* lB = lds2 + 8192;
        const int mt = blk >> 1, nt = blk & 1;
        const int l = tid & 63, w = tid >> 6;
        const int wm = w >> 1, wn = w & 1;
        const int q = l >> 4, r = l & 15;
        const float* Af = Wv + (size_t)mt * 128 * D_;
        const u16* Bb = WoTb + (size_t)nt * 16 * 8192;
        f32x4 acc[4][4];
#pragma unroll
        for (int a = 0; a < 4; ++a)
#pragma unroll
            for (int b = 0; b < 4; ++b) acc[a][b] = (f32x4){0.f, 0.f, 0.f, 0.f};
        for (int ks = 0; ks < 16; ++ks) {
            if (ks) __syncthreads();
            stage_f32(Af, D_, ks, lA, tid);
            stage_bf(Bb + (size_t)ks * 8192, lB, w, l);
            __syncthreads();
#pragma unroll
            for (int s = 0; s < 2; ++s) {
                bf16x8 af[4], bfr[4];
#pragma unroll
                for (int a = 0; a < 4; ++a) {
                    int row = wm * 64 + a * 16 + r;
                    af[a] = *reinterpret_cast<const bf16x8*>(&lA[row * 64 + (((s * 4 + q) ^ (row & 7)) << 3)]);
                }
#pragma unroll
                for (int b = 0; b < 4; ++b) {
                    int row = wn * 64 + b * 16 + r;
                    bfr[b] = *reinterpret_cast<const bf16x8*>(&lB[row * 64 + (((s * 4 + q) ^ (row & 7)) << 3)]);
                }
#pragma unroll
                for (int a = 0; a < 4; ++a)
#pragma unroll
                    for (int b = 0; b < 4; ++b)
                        acc[a][b] = __builtin_amdgcn_mfma_f32_16x16x32_bf16(af[a], bfr[b], acc[a][b], 0, 0, 0);
            }
        }
#pragma unroll
        for (int b = 0; b < 4; ++b) {
            int col = nt * 128 + wn * 64 + b * 16 + r;
#pragma unroll
            for (int a = 0; a < 4; ++a) {
#pragma unroll
                for (int j = 0; j < 4; ++j) {
                    int row = mt * 128 + wm * 64 + a * 16 + q * 4 + j;
                    Awo[(size_t)row * OUT_ + col] = acc[a][b][j];
                }
            }
        }
    } else {
        // Q[b][e] = sum_dd h_last[b][dd] * Wq[dd][e] + bq[e]
        float* hl = (float*)lds2;
        const int t = blk - 16;
        const int b = t >> 2, ec = t & 3;
        *reinterpret_cast<float4*>(&hl[tid * 4]) =
            *reinterpret_cast<const float4*>(&hlast[b * 1024 + tid * 4]);
        __syncthreads();
        const int e = ec * 256 + tid;
        float acc = bq[e];
#pragma unroll 8
        for (int dd = 0; dd < 1024; ++dd)
            acc += hl[dd] * Wq[(size_t)dd * 1024 + e];
        Qv[b * 1024 + e] = acc;
    }
}

// ================= K3: u[b] = Wk @ Q[b] ; cvo finish =================
__global__ __launch_bounds__(256) void k3(const float* __restrict__ Wk, const float* __restrict__ Qv,
                                          float* __restrict__ uvec,
                                          const float* __restrict__ cvop, const float* __restrict__ bo,
                                          float* __restrict__ cvo) {
    const int dc = blockIdx.x, b = blockIdx.y, tid = threadIdx.x;
    if (dc < 64) {
        const int w = tid >> 6, l = tid & 63;
        const int dbase = dc * 16 + w * 4;
        float4 qv[4];
#pragma unroll
        for (int p = 0; p < 4; ++p) qv[p] = *reinterpret_cast<const float4*>(&Qv[b * 1024 + p * 256 + l * 4]);
#pragma unroll
        for (int i = 0; i < 4; ++i) {
            const int d = dbase + i;
            const float* wr = &Wk[(size_t)d * 1024];
            float acc = 0.f;
#pragma unroll
            for (int p = 0; p < 4; ++p) {
                float4 wv = *reinterpret_cast<const float4*>(&wr[p * 256 + l * 4]);
                acc += wv.x * qv[p].x + wv.y * qv[p].y + wv.z * qv[p].z + wv.w * qv[p].w;
            }
#pragma unroll
            for (int s = 32; s > 0; s >>= 1) acc += __shfl_xor(acc, s);
            if (l == 0) uvec[b * 1024 + d] = acc;
        }
    } else if (b == 0) {
        float s = bo[tid];
#pragma unroll
        for (int j = 0; j < 16; ++j) s += cvop[j * 256 + tid];
        cvo[tid] = s;
    }
}

// ================= K24: fused h-GEMM (into LDS) + flash partial per (kc,b) =================
// h chunk [64][1024] bf16 lives in LDS, 8-B-granule XOR-swizzled by (row&7):
//   elem (r,c) at u16 index r*1024 + (((c>>2) ^ (r&7))<<2) + (c&3)
__global__ __launch_bounds__(512, 1) void k24(const float* __restrict__ x,
                                              const u16* __restrict__ WiTb,
                                              const float* __restrict__ bi,
                                              const float* __restrict__ uvec,
                                              float* __restrict__ part, float* __restrict__ msum) {
    __shared__ u16 hT[65536];     // 128 KB
    __shared__ u16 stg[8192];     // 16 KB WiT tile [128 hcols][64 k]
    __shared__ float sNp[64];
    __shared__ float pArr[64];
    const int kc = blockIdx.x, b = blockIdx.y;
    const int tid = threadIdx.x, w = tid >> 6, l = tid & 63;
    const int rg = w >> 1;        // row-group (16 x-rows each)
    const int half = w & 1;       // which 4 col-tiles of the 8 per nt
    const int q = l >> 4, r15 = l & 15;
    const int xrow = rg * 16 + r15;                 // 0..63 local row
    const size_t grow = (size_t)(b * S_ + kc * RC_ + xrow);

    // preload x fragments: frag f covers k = f*32 + q*8 .. +8  (K=256 -> 8 frags)
    bf16x8 xf[8];
    {
        const float* xr = x + grow * IN_ + q * 8;
#pragma unroll
        for (int f = 0; f < 8; ++f) {
            float4 v0 = *reinterpret_cast<const float4*>(xr + f * 32);
            float4 v1 = *reinterpret_cast<const float4*>(xr + f * 32 + 4);
            union { bf16x8 v; u16 e[8]; } pk;
            pk.e[0] = f2bf(v0.x); pk.e[1] = f2bf(v0.y); pk.e[2] = f2bf(v0.z); pk.e[3] = f2bf(v0.w);
            pk.e[4] = f2bf(v1.x); pk.e[5] = f2bf(v1.y); pk.e[6] = f2bf(v1.z); pk.e[7] = f2bf(v1.w);
            xf[f] = pk.v;
        }
    }

    // ---- GEMM: h = x @ WiT^T + bi, D = [hcol][xrow], written to LDS ----
    for (int nt = 0; nt < 8; ++nt) {
        f32x4 acc[4];
#pragma unroll
        for (int c = 0; c < 4; ++c) acc[c] = (f32x4){0.f, 0.f, 0.f, 0.f};
        for (int ks = 0; ks < 4; ++ks) {
            __syncthreads();   // protect stg reuse
            {   // stage 16 KB tile: 8 waves x 2 insts x 64 lanes x 16 B
                const u16* g = WiTb + (size_t)(nt * 4 + ks) * 8192 + w * 1024 + l * 8;
                u16* lp = stg + w * 1024 + l * 8;
                __builtin_amdgcn_global_load_lds((const __attribute__((address_space(1))) void*)g,
                                                 (__attribute__((address_space(3))) void*)lp, 16, 0, 0);
                __builtin_amdgcn_global_load_lds((const __attribute__((address_space(1))) void*)(g + 512),
                                                 (__attribute__((address_space(3))) void*)(lp + 512), 16, 0, 0);
            }
            __syncthreads();   // vmcnt drained by barrier semantics
#pragma unroll
            for (int s = 0; s < 2; ++s) {
#pragma unroll
                for (int c = 0; c < 4; ++c) {
                    int trow = half * 64 + c * 16 + r15;   // A-row (hcol local in tile)
                    bf16x8 af = *reinterpret_cast<const bf16x8*>(
                        &stg[trow * 64 + (((s * 4 + q) ^ (trow & 7)) << 3)]);
                    acc[c] = __builtin_amdgcn_mfma_f32_16x16x32_bf16(af, xf[ks * 2 + s], acc[c], 0, 0, 0);
                }
            }
        }
        // epilogue: lane holds h[hcol = ct*16+q*4+j][xrow], write 4 bf16 (one granule)
#pragma unroll
        for (int c = 0; c < 4; ++c) {
            int ct = nt * 8 + half * 4 + c;
            int colb = ct * 16 + q * 4;
            float4 bv = *reinterpret_cast<const float4*>(&bi[colb]);
            int gphys = (ct * 4 + q) ^ (xrow & 7);
            uint2 pk;
            pk.x = (unsigned)f2bf(acc[c][0] + bv.x) | ((unsigned)f2bf(acc[c][1] + bv.y) << 16);
            pk.y = (unsigned)f2bf(acc[c][2] + bv.z) | ((unsigned)f2bf(acc[c][3] + bv.w) << 16);
            *reinterpret_cast<uint2*>(&hT[xrow * 1024 + gphys * 4]) = pk;
        }
    }
    __syncthreads();

    // ---- scores: row r, score = (h[r]·u)/32.  Wave w owns rows w*8..w*8+8 ----
    float4 u0 = *reinterpret_cast<const float4*>(&uvec[b * 1024 + l * 4]);
    float4 u1 = *reinterpret_cast<const float4*>(&uvec[b * 1024 + 256 + l * 4]);
    float4 u2 = *reinterpret_cast<const float4*>(&uvec[b * 1024 + 512 + l * 4]);
    float4 u3 = *reinterpret_cast<const float4*>(&uvec[b * 1024 + 768 + l * 4]);
    for (int rr = 0; rr < 8; ++rr) {
        const int row = w * 8 + rr;
        const int r7 = row & 7;
        const int lx = l ^ r7;
        float acc = 0.f;
        {
            uint2 hv = *reinterpret_cast<const uint2*>(&hT[row * 1024 + lx * 4]);
            float2 p0 = bf2x2(hv.x), p1 = bf2x2(hv.y);
            acc += p0.x * u0.x + p0.y * u0.y + p1.x * u0.z + p1.y * u0.w;
        }
        {
            uint2 hv = *reinterpret_cast<const uint2*>(&hT[row * 1024 + (64 + lx) * 4]);
            float2 p0 = bf2x2(hv.x), p1 = bf2x2(hv.y);
            acc += p0.x * u1.x + p0.y * u1.y + p1.x * u1.z + p1.y * u1.w;
        }
        {
            uint2 hv = *reinterpret_cast<const uint2*>(&hT[row * 1024 + (128 + lx) * 4]);
            float2 p0 = bf2x2(hv.x), p1 = bf2x2(hv.y);
            acc += p0.x * u2.x + p0.y * u2.y + p1.x * u2.z + p1.y * u2.w;
        }
        {
            uint2 hv = *reinterpret_cast<const uint2*>(&hT[row * 1024 + (192 + lx) * 4]);
            float2 p0 = bf2x2(hv.x), p1 = bf2x2(hv.y);
            acc += p0.x * u3.x + p0.y * u3.y + p1.x * u3.z + p1.y * u3.w;
        }
#pragma unroll
        for (int s = 32; s > 0; s >>= 1) acc += __shfl_xor(acc, s);
        if (l == 0) sNp[row] = acc * 0.03125f;   // 1/sqrt(1024)
    }
    __syncthreads();

    // ---- local softmax (each wave redundantly) ----
    float sv = sNp[l];
    float mx = sv;
#pragma unroll
    for (int s = 32; s > 0; s >>= 1) mx = fmaxf(mx, __shfl_xor(mx, s));
    float p = __expf(sv - mx);
    float sum = p;
#pragma unroll
    for (int s = 32; s > 0; s >>= 1) sum += __shfl_xor(sum, s);
    if (w == 0) pArr[l] = p;
    if (tid == 0) { msum[(kc * 8 + b) * 2] = mx; msum[(kc * 8 + b) * 2 + 1] = sum; }
    __syncthreads();

    // ---- weighted sum: part[d] = sum_r p_r h[r][d].  Thread owns cols tid*2, tid*2+1 ----
    const int g = tid >> 1, hh = tid & 1;
    float a0 = 0.f, a1 = 0.f;
    for (int row = 0; row < 64; ++row) {
        float pk = pArr[row];
        unsigned hv = *reinterpret_cast<const unsigned*>(&hT[row * 1024 + ((g ^ (row & 7)) << 2) + hh * 2]);
        float2 xp = bf2x2(hv);
        a0 += pk * xp.x; a1 += pk * xp.y;
    }
    float2 st = {a0, a1};
    *reinterpret_cast<float2*>(&part[((size_t)(kc * 8 + b)) * D_ + tid * 2]) = st;
}

// ================= K5: combine partials -> hbar -> out = hbar@Awo + cvo =================
__global__ __launch_bounds__(256) void k5(const float* __restrict__ part, const float* __restrict__ msum,
                                          const float* __restrict__ Awo, const float* __restrict__ cvo,
                                          float* __restrict__ out) {
    const int b = blockIdx.x, tid = threadIdx.x, w = tid >> 6, l = tid & 63;
    __shared__ float hbar[1024];
    __shared__ float red[4][256];
    float m[KC_], sm[KC_];
    float M = -1e30f;
#pragma unroll
    for (int c = 0; c < KC_; ++c) {
        m[c] = msum[(c * 8 + b) * 2];
        sm[c] = msum[(c * 8 + b) * 2 + 1];
        M = fmaxf(M, m[c]);
    }
    float denom = 0.f;
    float wgt[KC_];
#pragma unroll
    for (int c = 0; c < KC_; ++c) { wgt[c] = __expf(m[c] - M); denom += wgt[c] * sm[c]; }
    const float inv = 1.f / denom;
    float h0 = 0.f, h1 = 0.f, h2 = 0.f, h3 = 0.f;
#pragma unroll
    for (int c = 0; c < KC_; ++c) {
        float4 pv = *reinterpret_cast<const float4*>(&part[((size_t)(c * 8 + b)) * D_ + tid * 4]);
        h0 += wgt[c] * pv.x; h1 += wgt[c] * pv.y; h2 += wgt[c] * pv.z; h3 += wgt[c] * pv.w;
    }
    hbar[tid * 4 + 0] = h0 * inv; hbar[tid * 4 + 1] = h1 * inv;
    hbar[tid * 4 + 2] = h2 * inv; hbar[tid * 4 + 3] = h3 * inv;
    __syncthreads();
    float o0 = 0.f, o1 = 0.f, o2 = 0.f, o3 = 0.f;
    for (int d = w * 256; d < w * 256 + 256; d += 4) {
        float4 hv = *reinterpret_cast<const float4*>(&hbar[d]);
#pragma unroll
        for (int j = 0; j < 4; ++j) {
            float hj = (j == 0) ? hv.x : (j == 1) ? hv.y : (j == 2) ? hv.z : hv.w;
            float4 av = *reinterpret_cast<const float4*>(&Awo[(size_t)(d + j) * OUT_ + l * 4]);
            o0 += hj * av.x; o1 += hj * av.y; o2 += hj * av.z; o3 += hj * av.w;
        }
    }
    red[w][l * 4 + 0] = o0; red[w][l * 4 + 1] = o1;
    red[w][l * 4 + 2] = o2; red[w][l * 4 + 3] = o3;
    __syncthreads();
    float r = red[0][tid] + red[1][tid] + red[2][tid] + red[3][tid] + cvo[tid];
    out[b * OUT_ + tid] = r;
}

extern "C" void kernel_launch(void* const* d_in, const int* in_sizes, int n_in,
                              void* d_out, int out_size, void* d_ws, size_t ws_size,
                              hipStream_t stream) {
    const float* x  = (const float*)d_in[0];
    const float* Wi = (const float*)d_in[1];
    const float* bi = (const float*)d_in[2];
    const float* Wq = (const float*)d_in[3];
    const float* bq = (const float*)d_in[4];
    const float* Wk = (const float*)d_in[5];
    // d_in[6] = bk : unused (softmax shift invariance)
    const float* Wv = (const float*)d_in[7];
    const float* bv = (const float*)d_in[8];
    const float* Wo = (const float*)d_in[9];
    const float* bo = (const float*)d_in[10];
    float* out = (float*)d_out;

    char* ws = (char*)d_ws;
    u16*   WiTb  = (u16*)  (ws + OFF_WITB);
    u16*   WoTb  = (u16*)  (ws + OFF_WOTB);
    float* hlast = (float*)(ws + OFF_HLAST);
    float* Qv    = (float*)(ws + OFF_QV);
    float* uv    = (float*)(ws + OFF_UV);
    float* Awo   = (float*)(ws + OFF_AWO);
    float* cvop  = (float*)(ws + OFF_CVOP);
    float* cvo   = (float*)(ws + OFF_CVO);
    float* part  = (float*)(ws + OFF_PART);
    float* msum  = (float*)(ws + OFF_MSUM);

    k1 <<<152,        256, 0, stream>>>(x, Wi, WiTb, bi, hlast, Wo, WoTb, bv, cvop);
    k2 <<<48,         256, 0, stream>>>(Wv, WoTb, Awo, hlast, Wq, bq, Qv);
    k3 <<<dim3(65,8), 256, 0, stream>>>(Wk, Qv, uv, cvop, bo, cvo);
    k24<<<dim3(32,8), 512, 0, stream>>>(x, WiTb, bi, uv, part, msum);
    k5 <<<8,          256, 0, stream>>>(part, msum, Awo, cvo, out);
}

// Round 7
// 197.162 us; speedup vs baseline: 1.1106x; 1.1106x over previous
//
#include <hip/hip_runtime.h>

typedef unsigned short u16;
typedef __attribute__((ext_vector_type(8))) short bf16x8;
typedef __attribute__((ext_vector_type(4))) float f32x4;

#define B_   8
#define S_   2048
#define IN_  256
#define D_   1024
#define OUT_ 256
#define KC_  32          // flash k-chunks
#define RC_  64          // rows per chunk

// ---- workspace offsets (bytes), total ~9.6 MB ----
#define OFF_WITB  0UL          // WiT tiles: 8 tr x 4 ks x 8192 u16 = 512K
#define OFF_WOTB  524288UL     // WoT tiles: 2 tr x 16 ks x 8192 u16 = 512K
#define OFF_WQB   1048576UL    // Wq tiles: 8 x 16 x 8192 u16 = 2M
#define OFF_WKB   3145728UL    // Wk tiles: 2M
#define OFF_AMAT  5242880UL    // Amat bf16 [1024][1024] = 2M  (Wq @ Wk^T)
#define OFF_AWO   7340032UL    // Awo f32 [1024][256] = 1M     (Wv @ Wo)
#define OFF_HLAST 8388608UL    // 8x1024 f32 (exact)
#define OFF_UV    8421376UL    // 8x1024 f32
#define OFF_C     8454144UL    // cvec 1024 f32 (Wk @ bq)
#define OFF_CVOP  8458240UL    // 16x256 f32
#define OFF_CVO   8474624UL    // 256 f32
#define OFF_PART  8475648UL    // 256x1024 f32 = 1M
#define OFF_MSUM  9524224UL    // 256x2 f32

static __device__ __forceinline__ float bf2f(u16 u) {
    union { unsigned i; float f; } x; x.i = ((unsigned)u) << 16; return x.f;
}
static __device__ __forceinline__ u16 f2bf(float f) {
    union { float f; unsigned i; } x; x.f = f;
    unsigned r = x.i + 0x7FFFu + ((x.i >> 16) & 1u);
    return (u16)(r >> 16);
}
static __device__ __forceinline__ float2 bf2x2(unsigned p) {
    union { unsigned i; float f; } a, b;
    a.i = p << 16;
    b.i = p & 0xFFFF0000u;
    float2 r; r.x = a.f; r.y = b.f; return r;
}

// Tiled-swizzled bf16 operand layout: element (rr in [0,128), cc in [0,64)) of tile
// (tr, ks) lives at u16 index (tr*KT + ks)*8192 + rr*64 + (((cc>>3) ^ (rr&7))<<3) + (cc&7).

// conv 128x64 f32 segment (row-major, leading dim lda) -> one swizzled bf16 tile
static __device__ __forceinline__ void conv_tile(const float* __restrict__ src, int lda,
                                                 u16* __restrict__ dst, int tid) {
#pragma unroll
    for (int i = 0; i < 4; ++i) {
        int it = i * 256 + tid;
        int rr = it >> 3, grp = it & 7;
        const float4* p = reinterpret_cast<const float4*>(&src[(size_t)rr * lda + grp * 8]);
        float4 v0 = p[0], v1 = p[1];
        int4 pk;
        pk.x = (int)f2bf(v0.x) | ((int)f2bf(v0.y) << 16);
        pk.y = (int)f2bf(v0.z) | ((int)f2bf(v0.w) << 16);
        pk.z = (int)f2bf(v1.x) | ((int)f2bf(v1.y) << 16);
        pk.w = (int)f2bf(v1.z) | ((int)f2bf(v1.w) << 16);
        *reinterpret_cast<int4*>(&dst[rr * 64 + ((grp ^ (rr & 7)) << 3)]) = pk;
    }
}

// ================= K1: operand prep =================
// blk 0..63   : WiT transpose -> WiTb
// blk 64..127 : WoT transpose -> WoTb
// blk 128..255: Wqb conv
// blk 256..383: Wkb conv
// blk 384..391: h_last[b] = x[b,S-1,:] @ Wi + bi  (f32 exact)
// blk 392..455: cvec = Wk @ bq
// blk 456..471: cvop partials (bv @ Wo)
__global__ __launch_bounds__(256) void k1(const float* __restrict__ x,
                                          const float* __restrict__ Wi, u16* __restrict__ WiTb,
                                          const float* __restrict__ bi, float* __restrict__ hlast,
                                          const float* __restrict__ Wo, u16* __restrict__ WoTb,
                                          const float* __restrict__ Wq, u16* __restrict__ Wqb,
                                          const float* __restrict__ Wk, u16* __restrict__ Wkb,
                                          const float* __restrict__ bq, float* __restrict__ cvec,
                                          const float* __restrict__ bv, float* __restrict__ cvop) {
    __shared__ float t64[64][65];
    const int blk = blockIdx.x, tid = threadIdx.x;
    if (blk < 64) {
        // WiT[n][k] = Wi[k][n]; Wi is [256][1024].  KT=4.
        const int n0 = (blk & 15) * 64, k0 = (blk >> 4) * 64;
        const int cc = tid & 63, rr = tid >> 6;
#pragma unroll
        for (int p = 0; p < 16; ++p) { int r = p * 4 + rr; t64[r][cc] = Wi[(k0 + r) * 1024 + n0 + cc]; }
        __syncthreads();
        const int ks = k0 >> 6;
#pragma unroll
        for (int g = 0; g < 2; ++g) {
            int it = g * 256 + tid;
            int nn = it >> 3, grp = it & 7;
            int n = n0 + nn, tr = n >> 7, rrow = n & 127;
            int4 pk;
            pk.x = (int)f2bf(t64[grp * 8 + 0][nn]) | ((int)f2bf(t64[grp * 8 + 1][nn]) << 16);
            pk.y = (int)f2bf(t64[grp * 8 + 2][nn]) | ((int)f2bf(t64[grp * 8 + 3][nn]) << 16);
            pk.z = (int)f2bf(t64[grp * 8 + 4][nn]) | ((int)f2bf(t64[grp * 8 + 5][nn]) << 16);
            pk.w = (int)f2bf(t64[grp * 8 + 6][nn]) | ((int)f2bf(t64[grp * 8 + 7][nn]) << 16);
            *reinterpret_cast<int4*>(&WiTb[(size_t)(tr * 4 + ks) * 8192 + rrow * 64 + ((grp ^ (rrow & 7)) << 3)]) = pk;
        }
    } else if (blk < 128) {
        // WoT[o][e] = Wo[e][o]; Wo is [1024][256].  KT=16.
        const int t = blk - 64;
        const int o0 = (t & 3) * 64, e0 = (t >> 2) * 64;
        const int cc = tid & 63, rr = tid >> 6;
#pragma unroll
        for (int p = 0; p < 16; ++p) { int r = p * 4 + rr; t64[r][cc] = Wo[(e0 + r) * 256 + o0 + cc]; }
        __syncthreads();
        const int ks = e0 >> 6;
#pragma unroll
        for (int g = 0; g < 2; ++g) {
            int it = g * 256 + tid;
            int nn = it >> 3, grp = it & 7;
            int o = o0 + nn, tr = o >> 7, rrow = o & 127;
            int4 pk;
            pk.x = (int)f2bf(t64[grp * 8 + 0][nn]) | ((int)f2bf(t64[grp * 8 + 1][nn]) << 16);
            pk.y = (int)f2bf(t64[grp * 8 + 2][nn]) | ((int)f2bf(t64[grp * 8 + 3][nn]) << 16);
            pk.z = (int)f2bf(t64[grp * 8 + 4][nn]) | ((int)f2bf(t64[grp * 8 + 5][nn]) << 16);
            pk.w = (int)f2bf(t64[grp * 8 + 6][nn]) | ((int)f2bf(t64[grp * 8 + 7][nn]) << 16);
            *reinterpret_cast<int4*>(&WoTb[(size_t)(tr * 16 + ks) * 8192 + rrow * 64 + ((grp ^ (rrow & 7)) << 3)]) = pk;
        }
    } else if (blk < 384) {
        const int seg = blk - 128;            // 0..255
        const int mat = seg >> 7;             // 0=Wq 1=Wk
        const int s2 = seg & 127;
        const int tr = s2 >> 4, ks = s2 & 15;
        const float* src = (mat == 0) ? Wq : Wk;
        u16* dst = (mat == 0) ? Wqb : Wkb;
        conv_tile(src + (size_t)tr * 128 * D_ + ks * 64, D_, dst + (size_t)(tr * 16 + ks) * 8192, tid);
    } else if (blk < 392) {
        // h_last[b][c] = sum_dd x[b,S-1,dd]*Wi[dd][c] + bi[c]   (pure f32)
        const int b = blk - 384;
        __shared__ float xl[256];
        xl[tid] = x[((size_t)(b * S_ + S_ - 1)) * IN_ + tid];
        __syncthreads();
        float4 acc = *reinterpret_cast<const float4*>(&bi[tid * 4]);
#pragma unroll 4
        for (int dd = 0; dd < 256; ++dd) {
            float xv = xl[dd];
            float4 wv = *reinterpret_cast<const float4*>(&Wi[(size_t)dd * 1024 + tid * 4]);
            acc.x += xv * wv.x; acc.y += xv * wv.y; acc.z += xv * wv.z; acc.w += xv * wv.w;
        }
        *reinterpret_cast<float4*>(&hlast[b * 1024 + tid * 4]) = acc;
    } else if (blk < 456) {
        // cvec[d] = sum_e Wk[d][e] * bq[e]
        const int b2 = blk - 392;
        const int w = tid >> 6, l = tid & 63;
        const int dbase = b2 * 16 + w * 4;
        float4 qv[4];
#pragma unroll
        for (int p = 0; p < 4; ++p) qv[p] = *reinterpret_cast<const float4*>(&bq[p * 256 + l * 4]);
#pragma unroll
        for (int i = 0; i < 4; ++i) {
            const int d = dbase + i;
            const float* wr = &Wk[(size_t)d * 1024];
            float acc = 0.f;
#pragma unroll
            for (int p = 0; p < 4; ++p) {
                float4 wv = *reinterpret_cast<const float4*>(&wr[p * 256 + l * 4]);
                acc += wv.x * qv[p].x + wv.y * qv[p].y + wv.z * qv[p].z + wv.w * qv[p].w;
            }
#pragma unroll
            for (int s = 32; s > 0; s >>= 1) acc += __shfl_xor(acc, s);
            if (l == 0) cvec[d] = acc;
        }
    } else {
        // cvop[chunk][o] = sum_{e in chunk} bv[e]*Wo[e][o]
        const int b2 = blk - 456;
        const int e0 = b2 * 64;
        float acc = 0.f;
        for (int e = 0; e < 64; ++e) acc += bv[e0 + e] * Wo[(size_t)(e0 + e) * 256 + tid];
        cvop[b2 * 256 + tid] = acc;
    }
}

// ---------------- staging helpers ----------------
static __device__ __forceinline__ void stage_bf(const u16* gtile, u16* lbuf, int w, int l) {
    const u16* g = gtile + w * 512 + l * 8;
    u16* lp = lbuf + w * 512;
#pragma unroll
    for (int i = 0; i < 4; ++i)
        __builtin_amdgcn_global_load_lds((const __attribute__((address_space(1))) void*)(g + i * 2048),
                                         (__attribute__((address_space(3))) void*)(lp + i * 2048), 16, 0, 0);
}
static __device__ __forceinline__ void stage_f32(const float* src, int lds_, int ks, u16* lbuf, int tid) {
#pragma unroll
    for (int i = 0; i < 4; ++i) {
        int it = i * 256 + tid;
        int row = it >> 3, grp = it & 7;
        const float4* p = reinterpret_cast<const float4*>(&src[(size_t)row * lds_ + ks * 64 + grp * 8]);
        float4 v0 = p[0], v1 = p[1];
        int4 pk;
        pk.x = (int)f2bf(v0.x) | ((int)f2bf(v0.y) << 16);
        pk.y = (int)f2bf(v0.z) | ((int)f2bf(v0.w) << 16);
        pk.z = (int)f2bf(v1.x) | ((int)f2bf(v1.y) << 16);
        pk.w = (int)f2bf(v1.z) | ((int)f2bf(v1.w) << 16);
        *reinterpret_cast<int4*>(&lbuf[row * 64 + ((grp ^ (row & 7)) << 3)]) = pk;
    }
}

// ================= K2: Amat = Wq@Wk^T (64 blk) + Awo = Wv@Wo (16 blk), all MFMA =================
__global__ __launch_bounds__(256) void k2(const u16* __restrict__ Wqb, const u16* __restrict__ Wkb,
                                          u16* __restrict__ Amat,
                                          const float* __restrict__ Wv, const u16* __restrict__ WoTb,
                                          float* __restrict__ Awo) {
    __shared__ u16 lA[8192];
    __shared__ u16 lB[8192];
    const int blk = blockIdx.x, tid = threadIdx.x;
    const int l = tid & 63, w = tid >> 6;
    const int wm = w >> 1, wn = w & 1;
    const int q = l >> 4, r = l & 15;
    f32x4 acc[4][4];
#pragma unroll
    for (int a = 0; a < 4; ++a)
#pragma unroll
        for (int b = 0; b < 4; ++b) acc[a][b] = (f32x4){0.f, 0.f, 0.f, 0.f};

    if (blk < 64) {
        const int mt = blk >> 3, nt = blk & 7;
        const u16* Ab = Wqb + (size_t)mt * 16 * 8192;
        const u16* Bb = Wkb + (size_t)nt * 16 * 8192;
        for (int ks = 0; ks < 16; ++ks) {
            if (ks) __syncthreads();
            stage_bf(Ab + (size_t)ks * 8192, lA, w, l);
            stage_bf(Bb + (size_t)ks * 8192, lB, w, l);
            __syncthreads();
#pragma unroll
            for (int s = 0; s < 2; ++s) {
                bf16x8 af[4], bfr[4];
#pragma unroll
                for (int a = 0; a < 4; ++a) {
                    int row = wm * 64 + a * 16 + r;
                    af[a] = *reinterpret_cast<const bf16x8*>(&lA[row * 64 + (((s * 4 + q) ^ (row & 7)) << 3)]);
                }
#pragma unroll
                for (int b = 0; b < 4; ++b) {
                    int row = wn * 64 + b * 16 + r;
                    bfr[b] = *reinterpret_cast<const bf16x8*>(&lB[row * 64 + (((s * 4 + q) ^ (row & 7)) << 3)]);
                }
#pragma unroll
                for (int a = 0; a < 4; ++a)
#pragma unroll
                    for (int b = 0; b < 4; ++b)
                        acc[a][b] = __builtin_amdgcn_mfma_f32_16x16x32_bf16(af[a], bfr[b], acc[a][b], 0, 0, 0);
            }
        }
#pragma unroll
        for (int b = 0; b < 4; ++b) {
            int col = nt * 128 + wn * 64 + b * 16 + r;
#pragma unroll
            for (int a = 0; a < 4; ++a)
#pragma unroll
                for (int j = 0; j < 4; ++j) {
                    int row = mt * 128 + wm * 64 + a * 16 + q * 4 + j;
                    Amat[(size_t)row * D_ + col] = f2bf(acc[a][b][j]);
                }
        }
    } else {
        const int t = blk - 64;
        const int mt = t >> 1, nt = t & 1;
        const float* Af = Wv + (size_t)mt * 128 * D_;
        const u16* Bb = WoTb + (size_t)nt * 16 * 8192;
        for (int ks = 0; ks < 16; ++ks) {
            if (ks) __syncthreads();
            stage_f32(Af, D_, ks, lA, tid);
            stage_bf(Bb + (size_t)ks * 8192, lB, w, l);
            __syncthreads();
#pragma unroll
            for (int s = 0; s < 2; ++s) {
                bf16x8 af[4], bfr[4];
#pragma unroll
                for (int a = 0; a < 4; ++a) {
                    int row = wm * 64 + a * 16 + r;
                    af[a] = *reinterpret_cast<const bf16x8*>(&lA[row * 64 + (((s * 4 + q) ^ (row & 7)) << 3)]);
                }
#pragma unroll
                for (int b = 0; b < 4; ++b) {
                    int row = wn * 64 + b * 16 + r;
                    bfr[b] = *reinterpret_cast<const bf16x8*>(&lB[row * 64 + (((s * 4 + q) ^ (row & 7)) << 3)]);
                }
#pragma unroll
                for (int a = 0; a < 4; ++a)
#pragma unroll
                    for (int b = 0; b < 4; ++b)
                        acc[a][b] = __builtin_amdgcn_mfma_f32_16x16x32_bf16(af[a], bfr[b], acc[a][b], 0, 0, 0);
            }
        }
#pragma unroll
        for (int b = 0; b < 4; ++b) {
            int col = nt * 128 + wn * 64 + b * 16 + r;
#pragma unroll
            for (int a = 0; a < 4; ++a)
#pragma unroll
                for (int j = 0; j < 4; ++j) {
                    int row = mt * 128 + wm * 64 + a * 16 + q * 4 + j;
                    Awo[(size_t)row * OUT_ + col] = acc[a][b][j];
                }
        }
    }
}

// ================= K3: u[b] = hlast[b] @ Amat + cvec ; cvo finish =================
__global__ __launch_bounds__(256) void k3(const float* __restrict__ hlast, const u16* __restrict__ Amat,
                                          const float* __restrict__ cvec, float* __restrict__ uvec,
                                          const float* __restrict__ cvop, const float* __restrict__ bo,
                                          float* __restrict__ cvo) {
    const int blk = blockIdx.x, tid = threadIdx.x;
    if (blk < 128) {
        const int b = blk >> 4, dc = blk & 15;
        __shared__ float hl[1024];
        __shared__ float red[4][64];
        *reinterpret_cast<float4*>(&hl[tid * 4]) =
            *reinterpret_cast<const float4*>(&hlast[b * 1024 + tid * 4]);
        __syncthreads();
        const int dl = tid & 63, qd = tid >> 6;
        const int d = dc * 64 + dl;
        float ac[8] = {0.f, 0.f, 0.f, 0.f, 0.f, 0.f, 0.f, 0.f};
        for (int dp = qd * 256; dp < qd * 256 + 256; dp += 8) {
            float hh[8];
#pragma unroll
            for (int i = 0; i < 8; ++i) hh[i] = hl[dp + i];
#pragma unroll
            for (int i = 0; i < 8; ++i) ac[i] += hh[i] * bf2f(Amat[(size_t)(dp + i) * D_ + d]);
        }
        float acc = ((ac[0] + ac[1]) + (ac[2] + ac[3])) + ((ac[4] + ac[5]) + (ac[6] + ac[7]));
        red[qd][dl] = acc;
        __syncthreads();
        if (qd == 0) {
            float s = red[0][dl] + red[1][dl] + red[2][dl] + red[3][dl];
            uvec[b * 1024 + d] = s + cvec[d];
        }
    } else {
        float s = bo[tid];
#pragma unroll
        for (int j = 0; j < 16; ++j) s += cvop[j * 256 + tid];
        cvo[tid] = s;
    }
}

// ================= K24: fused h-GEMM (into LDS) + flash partial per (kc,b) =================
// h chunk [64][1024] bf16 lives in LDS, 8-B-granule XOR-swizzled by (row&7):
//   elem (r,c) at u16 index r*1024 + (((c>>2) ^ (r&7))<<2) + (c&3)
__global__ __launch_bounds__(512, 1) void k24(const float* __restrict__ x,
                                              const u16* __restrict__ WiTb,
                                              const float* __restrict__ bi,
                                              const float* __restrict__ uvec,
                                              float* __restrict__ part, float* __restrict__ msum) {
    __shared__ u16 hT[65536];     // 128 KB
    __shared__ u16 stg[8192];     // 16 KB WiT tile [128 hcols][64 k]
    __shared__ float sNp[64];
    __shared__ float pArr[64];
    const int kc = blockIdx.x, b = blockIdx.y;
    const int tid = threadIdx.x, w = tid >> 6, l = tid & 63;
    const int rg = w >> 1;        // row-group (16 x-rows each)
    const int half = w & 1;       // which 4 col-tiles of the 8 per nt
    const int q = l >> 4, r15 = l & 15;
    const int xrow = rg * 16 + r15;                 // 0..63 local row
    const size_t grow = (size_t)(b * S_ + kc * RC_ + xrow);

    // preload x fragments: frag f covers k = f*32 + q*8 .. +8  (K=256 -> 8 frags)
    bf16x8 xf[8];
    {
        const float* xr = x + grow * IN_ + q * 8;
#pragma unroll
        for (int f = 0; f < 8; ++f) {
            float4 v0 = *reinterpret_cast<const float4*>(xr + f * 32);
            float4 v1 = *reinterpret_cast<const float4*>(xr + f * 32 + 4);
            union { bf16x8 v; u16 e[8]; } pk;
            pk.e[0] = f2bf(v0.x); pk.e[1] = f2bf(v0.y); pk.e[2] = f2bf(v0.z); pk.e[3] = f2bf(v0.w);
            pk.e[4] = f2bf(v1.x); pk.e[5] = f2bf(v1.y); pk.e[6] = f2bf(v1.z); pk.e[7] = f2bf(v1.w);
            xf[f] = pk.v;
        }
    }

    // ---- GEMM: h = x @ WiT^T + bi, D = [hcol][xrow], written to LDS ----
    for (int nt = 0; nt < 8; ++nt) {
        f32x4 acc[4];
#pragma unroll
        for (int c = 0; c < 4; ++c) acc[c] = (f32x4){0.f, 0.f, 0.f, 0.f};
        for (int ks = 0; ks < 4; ++ks) {
            __syncthreads();   // protect stg reuse
            {   // stage 16 KB tile: 8 waves x 2 insts x 64 lanes x 16 B
                const u16* g = WiTb + (size_t)(nt * 4 + ks) * 8192 + w * 1024 + l * 8;
                u16* lp = stg + w * 1024 + l * 8;
                __builtin_amdgcn_global_load_lds((const __attribute__((address_space(1))) void*)g,
                                                 (__attribute__((address_space(3))) void*)lp, 16, 0, 0);
                __builtin_amdgcn_global_load_lds((const __attribute__((address_space(1))) void*)(g + 512),
                                                 (__attribute__((address_space(3))) void*)(lp + 512), 16, 0, 0);
            }
            __syncthreads();   // vmcnt drained by barrier semantics
#pragma unroll
            for (int s = 0; s < 2; ++s) {
#pragma unroll
                for (int c = 0; c < 4; ++c) {
                    int trow = half * 64 + c * 16 + r15;   // A-row (hcol local in tile)
                    bf16x8 af = *reinterpret_cast<const bf16x8*>(
                        &stg[trow * 64 + (((s * 4 + q) ^ (trow & 7)) << 3)]);
                    acc[c] = __builtin_amdgcn_mfma_f32_16x16x32_bf16(af, xf[ks * 2 + s], acc[c], 0, 0, 0);
                }
            }
        }
        // epilogue: lane holds h[hcol = ct*16+q*4+j][xrow], write 4 bf16 (one granule)
#pragma unroll
        for (int c = 0; c < 4; ++c) {
            int ct = nt * 8 + half * 4 + c;
            int colb = ct * 16 + q * 4;
            float4 bv = *reinterpret_cast<const float4*>(&bi[colb]);
            int gphys = (ct * 4 + q) ^ (xrow & 7);
            uint2 pk;
            pk.x = (unsigned)f2bf(acc[c][0] + bv.x) | ((unsigned)f2bf(acc[c][1] + bv.y) << 16);
            pk.y = (unsigned)f2bf(acc[c][2] + bv.z) | ((unsigned)f2bf(acc[c][3] + bv.w) << 16);
            *reinterpret_cast<uint2*>(&hT[xrow * 1024 + gphys * 4]) = pk;
        }
    }
    __syncthreads();

    // ---- scores: row r, score = (h[r]·u)/32.  Wave w owns rows w*8..w*8+8 ----
    float4 u0 = *reinterpret_cast<const float4*>(&uvec[b * 1024 + l * 4]);
    float4 u1 = *reinterpret_cast<const float4*>(&uvec[b * 1024 + 256 + l * 4]);
    float4 u2 = *reinterpret_cast<const float4*>(&uvec[b * 1024 + 512 + l * 4]);
    float4 u3 = *reinterpret_cast<const float4*>(&uvec[b * 1024 + 768 + l * 4]);
    for (int rr = 0; rr < 8; ++rr) {
        const int row = w * 8 + rr;
        const int r7 = row & 7;
        const int lx = l ^ r7;
        float acc = 0.f;
        {
            uint2 hv = *reinterpret_cast<const uint2*>(&hT[row * 1024 + lx * 4]);
            float2 p0 = bf2x2(hv.x), p1 = bf2x2(hv.y);
            acc += p0.x * u0.x + p0.y * u0.y + p1.x * u0.z + p1.y * u0.w;
        }
        {
            uint2 hv = *reinterpret_cast<const uint2*>(&hT[row * 1024 + (64 + lx) * 4]);
            float2 p0 = bf2x2(hv.x), p1 = bf2x2(hv.y);
            acc += p0.x * u1.x + p0.y * u1.y + p1.x * u1.z + p1.y * u1.w;
        }
        {
            uint2 hv = *reinterpret_cast<const uint2*>(&hT[row * 1024 + (128 + lx) * 4]);
            float2 p0 = bf2x2(hv.x), p1 = bf2x2(hv.y);
            acc += p0.x * u2.x + p0.y * u2.y + p1.x * u2.z + p1.y * u2.w;
        }
        {
            uint2 hv = *reinterpret_cast<const uint2*>(&hT[row * 1024 + (192 + lx) * 4]);
            float2 p0 = bf2x2(hv.x), p1 = bf2x2(hv.y);
            acc += p0.x * u3.x + p0.y * u3.y + p1.x * u3.z + p1.y * u3.w;
        }
#pragma unroll
        for (int s = 32; s > 0; s >>= 1) acc += __shfl_xor(acc, s);
        if (l == 0) sNp[row] = acc * 0.03125f;   // 1/sqrt(1024)
    }
    __syncthreads();

    // ---- local softmax (each wave redundantly) ----
    float sv = sNp[l];
    float mx = sv;
#pragma unroll
    for (int s = 32; s > 0; s >>= 1) mx = fmaxf(mx, __shfl_xor(mx, s));
    float p = __expf(sv - mx);
    float sum = p;
#pragma unroll
    for (int s = 32; s > 0; s >>= 1) sum += __shfl_xor(sum, s);
    if (w == 0) pArr[l] = p;
    if (tid == 0) { msum[(kc * 8 + b) * 2] = mx; msum[(kc * 8 + b) * 2 + 1] = sum; }
    __syncthreads();

    // ---- weighted sum: part[d] = sum_r p_r h[r][d].  Thread owns cols tid*2, tid*2+1 ----
    const int g = tid >> 1, hh = tid & 1;
    float a0 = 0.f, a1 = 0.f;
    for (int row = 0; row < 64; ++row) {
        float pk = pArr[row];
        unsigned hv = *reinterpret_cast<const unsigned*>(&hT[row * 1024 + ((g ^ (row & 7)) << 2) + hh * 2]);
        float2 xp = bf2x2(hv);
        a0 += pk * xp.x; a1 += pk * xp.y;
    }
    float2 st = {a0, a1};
    *reinterpret_cast<float2*>(&part[((size_t)(kc * 8 + b)) * D_ + tid * 2]) = st;
}

// ================= K5: combine partials -> hbar -> out = hbar@Awo + cvo =================
__global__ __launch_bounds__(256) void k5(const float* __restrict__ part, const float* __restrict__ msum,
                                          const float* __restrict__ Awo, const float* __restrict__ cvo,
                                          float* __restrict__ out) {
    const int b = blockIdx.x, tid = threadIdx.x, w = tid >> 6, l = tid & 63;
    __shared__ float hbar[1024];
    __shared__ float red[4][256];
    float m[KC_], sm[KC_];
    float M = -1e30f;
#pragma unroll
    for (int c = 0; c < KC_; ++c) {
        m[c] = msum[(c * 8 + b) * 2];
        sm[c] = msum[(c * 8 + b) * 2 + 1];
        M = fmaxf(M, m[c]);
    }
    float denom = 0.f;
    float wgt[KC_];
#pragma unroll
    for (int c = 0; c < KC_; ++c) { wgt[c] = __expf(m[c] - M); denom += wgt[c] * sm[c]; }
    const float inv = 1.f / denom;
    float h0 = 0.f, h1 = 0.f, h2 = 0.f, h3 = 0.f;
#pragma unroll
    for (int c = 0; c < KC_; ++c) {
        float4 pv = *reinterpret_cast<const float4*>(&part[((size_t)(c * 8 + b)) * D_ + tid * 4]);
        h0 += wgt[c] * pv.x; h1 += wgt[c] * pv.y; h2 += wgt[c] * pv.z; h3 += wgt[c] * pv.w;
    }
    hbar[tid * 4 + 0] = h0 * inv; hbar[tid * 4 + 1] = h1 * inv;
    hbar[tid * 4 + 2] = h2 * inv; hbar[tid * 4 + 3] = h3 * inv;
    __syncthreads();
    float o0 = 0.f, o1 = 0.f, o2 = 0.f, o3 = 0.f;
    for (int d = w * 256; d < w * 256 + 256; d += 4) {
        float4 hv = *reinterpret_cast<const float4*>(&hbar[d]);
#pragma unroll
        for (int j = 0; j < 4; ++j) {
            float hj = (j == 0) ? hv.x : (j == 1) ? hv.y : (j == 2) ? hv.z : hv.w;
            float4 av = *reinterpret_cast<const float4*>(&Awo[(size_t)(d + j) * OUT_ + l * 4]);
            o0 += hj * av.x; o1 += hj * av.y; o2 += hj * av.z; o3 += hj * av.w;
        }
    }
    red[w][l * 4 + 0] = o0; red[w][l * 4 + 1] = o1;
    red[w][l * 4 + 2] = o2; red[w][l * 4 + 3] = o3;
    __syncthreads();
    float r = red[0][tid] + red[1][tid] + red[2][tid] + red[3][tid] + cvo[tid];
    out[b * OUT_ + tid] = r;
}

extern "C" void kernel_launch(void* const* d_in, const int* in_sizes, int n_in,
                              void* d_out, int out_size, void* d_ws, size_t ws_size,
                              hipStream_t stream) {
    const float* x  = (const float*)d_in[0];
    const float* Wi = (const float*)d_in[1];
    const float* bi = (const float*)d_in[2];
    const float* Wq = (const float*)d_in[3];
    const float* bq = (const float*)d_in[4];
    const float* Wk = (const float*)d_in[5];
    // d_in[6] = bk : unused (softmax shift invariance)
    const float* Wv = (const float*)d_in[7];
    const float* bv = (const float*)d_in[8];
    const float* Wo = (const float*)d_in[9];
    const float* bo = (const float*)d_in[10];
    float* out = (float*)d_out;

    char* ws = (char*)d_ws;
    u16*   WiTb  = (u16*)  (ws + OFF_WITB);
    u16*   WoTb  = (u16*)  (ws + OFF_WOTB);
    u16*   Wqb   = (u16*)  (ws + OFF_WQB);
    u16*   Wkb   = (u16*)  (ws + OFF_WKB);
    u16*   Amat  = (u16*)  (ws + OFF_AMAT);
    float* Awo   = (float*)(ws + OFF_AWO);
    float* hlast = (float*)(ws + OFF_HLAST);
    float* uv    = (float*)(ws + OFF_UV);
    float* cvec  = (float*)(ws + OFF_C);
    float* cvop  = (float*)(ws + OFF_CVOP);
    float* cvo   = (float*)(ws + OFF_CVO);
    float* part  = (float*)(ws + OFF_PART);
    float* msum  = (float*)(ws + OFF_MSUM);

    k1 <<<472,        256, 0, stream>>>(x, Wi, WiTb, bi, hlast, Wo, WoTb, Wq, Wqb, Wk, Wkb,
                                        bq, cvec, bv, cvop);
    k2 <<<80,         256, 0, stream>>>(Wqb, Wkb, Amat, Wv, WoTb, Awo);
    k3 <<<129,        256, 0, stream>>>(hlast, Amat, cvec, uv, cvop, bo, cvo);
    k24<<<dim3(32,8), 512, 0, stream>>>(x, WiTb, bi, uv, part, msum);
    k5 <<<8,          256, 0, stream>>>(part, msum, Awo, cvo, out);
}